// Round 4
// baseline (560.670 us; speedup 1.0000x reference)
//
#include <hip/hip_runtime.h>
#include <stdint.h>

typedef unsigned int u32;
typedef unsigned long long u64;
typedef unsigned short u16;

// Key space: b in [0,4), parent in [0,512)^3 -> 2^29 keys, 2^23 bitmap words.
#define TOTAL_WORDS 8388608u

__device__ __forceinline__ u32 make_key(int4 c) {
    // c = [b,x,y,z]; key = ((b*512 + z/2)*512 + y/2)*512 + x/2
    return ((((u32)c.x * 512u + ((u32)c.w >> 1)) * 512u + ((u32)c.z >> 1)) * 512u)
           + ((u32)c.y >> 1);
}

__global__ void fill_u32(u32* p, u32 pattern, u32 n) {
    u32 i = blockIdx.x * blockDim.x + threadIdx.x;
    if (i < n) p[i] = pattern;
}

// ---- pass partition (only used when P > 1) ----
__global__ void hist_kernel(const int4* __restrict__ coords, u32* __restrict__ pass_cnt,
                            int n, u32 shift, u32 P) {
    extern __shared__ u32 h[];
    for (u32 i = threadIdx.x; i < P; i += blockDim.x) h[i] = 0;
    __syncthreads();
    int i = blockIdx.x * blockDim.x + threadIdx.x;
    if (i < n) atomicAdd(&h[make_key(coords[i]) >> shift], 1u);
    __syncthreads();
    for (u32 b = threadIdx.x; b < P; b += blockDim.x)
        if (h[b]) atomicAdd(&pass_cnt[b], h[b]);
}

// exclusive scan of gs[0..G) in place; adds base counter[0]; counter[0]+=total.
__global__ void scan_groups(u32* __restrict__ gs, u32 G, u32* __restrict__ counter) {
    __shared__ u32 s[1024];
    int t = threadIdx.x;
    u32 items = (G + 1023u) >> 10;
    u32 base = counter[0];
    u32 v[32]; u32 sum = 0;
    for (u32 j = 0; j < items; ++j) {
        u32 idx = (u32)t * items + j;
        v[j] = (idx < G) ? gs[idx] : 0u;
        sum += v[j];
    }
    s[t] = sum; __syncthreads();
    for (int d = 1; d < 1024; d <<= 1) {
        u32 add = (t >= d) ? s[t - d] : 0u;
        __syncthreads(); s[t] += add; __syncthreads();
    }
    u32 excl = s[t] - sum + base;
    for (u32 j = 0; j < items; ++j) {
        u32 idx = (u32)t * items + j;
        if (idx < G) { u32 x = v[j]; gs[idx] = excl; excl += x; }
    }
    if (t == 1023) counter[0] = base + s[1023];
}

__global__ void copy_u32(const u32* __restrict__ src, u32* __restrict__ dst, u32 n) {
    u32 i = blockIdx.x * blockDim.x + threadIdx.x;
    if (i < n) dst[i] = src[i];
}

__global__ void scatter_kernel(const int4* __restrict__ coords, u32* __restrict__ records,
                               u32* __restrict__ pass_cur, int n, u32 shift, u32 P) {
    extern __shared__ u32 sh[];
    u32* cnt = sh; u32* base = sh + P;
    for (u32 i = threadIdx.x; i < P; i += blockDim.x) cnt[i] = 0;
    __syncthreads();
    int i = blockIdx.x * blockDim.x + threadIdx.x;
    u32 bin = 0, rec = 0, loc = 0; bool valid = (i < n);
    if (valid) {
        int4 c = coords[i];
        u32 key = make_key(c);
        u32 off = ((u32)c.y & 1u) | (((u32)c.z & 1u) << 1) | (((u32)c.w & 1u) << 2);
        rec = (key << 3) | off;
        bin = key >> shift;
        loc = atomicAdd(&cnt[bin], 1u);
    }
    __syncthreads();
    for (u32 b = threadIdx.x; b < P; b += blockDim.x)
        if (cnt[b]) base[b] = atomicAdd(&pass_cur[b], cnt[b]);
    __syncthreads();
    if (valid) records[base[bin] + loc] = rec;
}

// ---- bitmap build ----
__global__ void build_bitmap_direct(const int4* __restrict__ coords, u64* __restrict__ bitmap, int n) {
    int i = blockIdx.x * blockDim.x + threadIdx.x;
    if (i >= n) return;
    u32 key = make_key(coords[i]);
    atomicOr(&bitmap[key >> 6], 1ull << (key & 63u));
}

__global__ void build_bitmap_rec(const u32* __restrict__ records, const u32* __restrict__ pass_base,
                                 u64* __restrict__ bitmap, int n, u32 p, u32 P, u32 mask) {
    u32 start = pass_base[p];
    u32 end = (p + 1 < P) ? pass_base[p + 1] : (u32)n;
    for (u32 i = start + blockIdx.x * blockDim.x + threadIdx.x; i < end;
         i += gridDim.x * blockDim.x) {
        u32 lk = (records[i] >> 3) & mask;
        atomicOr(&bitmap[lk >> 6], 1ull << (lk & 63u));
    }
}

// one 64-thread block per 256-word group
__global__ void rank_build(const u64* __restrict__ bitmap, u16* __restrict__ wo16,
                           u32* __restrict__ gsums) {
    __shared__ u32 s[64];
    int t = threadIdx.x;
    u32 wbase = blockIdx.x * 256u + (u32)t * 4u;
    u32 pc[4]; u32 sum = 0;
    #pragma unroll
    for (int j = 0; j < 4; ++j) { pc[j] = (u32)__popcll(bitmap[wbase + j]); sum += pc[j]; }
    s[t] = sum; __syncthreads();
    for (int d = 1; d < 64; d <<= 1) {
        u32 add = (t >= d) ? s[t - d] : 0u;
        __syncthreads(); s[t] += add; __syncthreads();
    }
    u32 excl = s[t] - sum;
    #pragma unroll
    for (int j = 0; j < 4; ++j) { wo16[wbase + j] = (u16)excl; excl += pc[j]; }
    if (t == 63) gsums[blockIdx.x] = s[63];
}

// ---- accumulate feats (fp32, exact integer sums) ----
__device__ __forceinline__ u32 rank_of(u32 lk, const u64* bitmap, const u16* wo16, const u32* gbase) {
    u32 w = lk >> 6, b = lk & 63u;
    return gbase[w >> 8] + (u32)wo16[w] + (u32)__popcll(bitmap[w] & ((1ull << b) - 1ull));
}

__global__ void accumulate_direct(const int4* __restrict__ coords, const float* __restrict__ kern,
                                  const u64* __restrict__ bitmap, const u16* __restrict__ wo16,
                                  const u32* __restrict__ gbase, float* __restrict__ feats, int n) {
    int i = blockIdx.x * blockDim.x + threadIdx.x;
    if (i >= n) return;
    int4 c = coords[i];
    u32 off = ((u32)c.y & 1u) | (((u32)c.z & 1u) << 1) | (((u32)c.w & 1u) << 2);
    float contrib = (float)(1u << off) * kern[off];
    atomicAdd(&feats[rank_of(make_key(c), bitmap, wo16, gbase)], contrib);
}

__global__ void accumulate_rec(const u32* __restrict__ records, const u32* __restrict__ pass_base,
                               const float* __restrict__ kern, const u64* __restrict__ bitmap,
                               const u16* __restrict__ wo16, const u32* __restrict__ gbase,
                               float* __restrict__ feats, int n, u32 p, u32 P, u32 mask) {
    u32 start = pass_base[p];
    u32 end = (p + 1 < P) ? pass_base[p + 1] : (u32)n;
    for (u32 i = start + blockIdx.x * blockDim.x + threadIdx.x; i < end;
         i += gridDim.x * blockDim.x) {
        u32 rec = records[i];
        u32 off = rec & 7u;
        float contrib = (float)(1u << off) * kern[off];
        atomicAdd(&feats[rank_of((rec >> 3) & mask, bitmap, wo16, gbase)], contrib);
    }
}

// decode set bits in ascending order -> fp32 coords rows [b,x,y,z]
__global__ void emit_coords(const u64* __restrict__ bitmap, const u16* __restrict__ wo16,
                            const u32* __restrict__ gbase, float4* __restrict__ out_rows,
                            u32 W, u32 p, u32 shift) {
    u32 w = blockIdx.x * blockDim.x + threadIdx.x;
    if (w >= W) return;
    u64 bits = bitmap[w];
    if (!bits) return;
    u32 rank = gbase[w >> 8] + (u32)wo16[w];
    u32 keybase = (p << shift) + (w << 6);
    while (bits) {
        u32 b = (u32)__builtin_ctzll(bits);
        bits &= bits - 1;
        u32 key = keybase + b;
        float4 row;
        row.x = (float)(key >> 27);           // b
        row.y = (float)(key & 511u);          // x
        row.z = (float)((key >> 9) & 511u);   // y
        row.w = (float)((key >> 18) & 511u);  // z
        out_rows[rank++] = row;
    }
}

__global__ void pad_fill(float4* __restrict__ rows, const u32* __restrict__ counter, int n) {
    int i = blockIdx.x * blockDim.x + threadIdx.x;
    if (i < n && (u32)i >= counter[0]) rows[i] = make_float4(-1.f, -1.f, -1.f, -1.f);
}

extern "C" void kernel_launch(void* const* d_in, const int* in_sizes, int n_in,
                              void* d_out, int out_size, void* d_ws, size_t ws_size,
                              hipStream_t stream) {
    const int n = in_sizes[0] / 4;                 // 4,000,000 points
    const int4* coords = (const int4*)d_in[0];
    const float* kern  = (const float*)d_in[1];

    // smallest P (power of 2, <=4096) whose ws footprint fits
    u32 P = 4096, log2P = 12;
    for (u32 lp = 0; lp <= 12; ++lp) {
        u32 p = 1u << lp;
        size_t W = TOTAL_WORDS / p;
        size_t total = W * 10 + (W / 256) * 4 + 8 + (size_t)p * 8;
        if (total <= ws_size) { P = p; log2P = lp; break; }
    }
    const u32 W = TOTAL_WORDS / P;
    const u32 G = W / 256u;
    const u32 shift = 29u - log2P;
    const u32 mask = (shift >= 32u) ? 0xFFFFFFFFu : ((1u << shift) - 1u);

    char* ws = (char*)d_ws;
    u64* bitmap    = (u64*)ws;                                    // W*8
    u16* wo16      = (u16*)(ws + (size_t)W * 8);                  // W*2
    u32* gbase     = (u32*)(ws + (size_t)W * 10);                 // G*4
    u32* counter   = (u32*)(ws + (size_t)W * 10 + (size_t)G * 4); // 2*4
    u32* pass_base = counter + 2;                                 // P*4
    u32* pass_cur  = pass_base + P;                               // P*4

    // d_out (float32): coords rows n*float4 = 64 MB, then feats n*fp32 = 16 MB
    float4* out_rows = (float4*)d_out;
    float*  feats    = (float*)((char*)d_out + (size_t)n * 16);
    // records (P>1): upper 16 MB of coords region. Safe: rows written before pass p
    // end at 16*Ucum(p) <= 48e6 + 4*Ncum(p) since Ucum<=Ncum<=4e6.
    u32* records = (u32*)((char*)d_out + (size_t)n * 12);

    fill_u32<<<((u32)n + 255) / 256, 256, 0, stream>>>((u32*)feats, 0u, (u32)n);
    fill_u32<<<1, 64, 0, stream>>>(counter, 0u, 2u);

    if (P > 1) {
        fill_u32<<<(P + 255) / 256, 256, 0, stream>>>(pass_base, 0u, P);
        hist_kernel<<<((u32)n + 255) / 256, 256, P * 4, stream>>>(coords, pass_base, n, shift, P);
        scan_groups<<<1, 1024, 0, stream>>>(pass_base, P, counter + 1);
        copy_u32<<<(P + 255) / 256, 256, 0, stream>>>(pass_base, pass_cur, P);
        scatter_kernel<<<((u32)n + 255) / 256, 256, P * 8, stream>>>(coords, records, pass_cur,
                                                                     n, shift, P);
    }

    u32 per_pass = (u32)n / P + 1u;
    u32 gridB = (per_pass + 255u) / 256u + 1u;
    if (gridB > 4096u) gridB = 4096u;

    for (u32 p = 0; p < P; ++p) {
        fill_u32<<<(W * 2 + 255) / 256, 256, 0, stream>>>((u32*)bitmap, 0u, W * 2);
        if (P == 1)
            build_bitmap_direct<<<((u32)n + 255) / 256, 256, 0, stream>>>(coords, bitmap, n);
        else
            build_bitmap_rec<<<gridB, 256, 0, stream>>>(records, pass_base, bitmap, n, p, P, mask);
        rank_build<<<G, 64, 0, stream>>>(bitmap, wo16, gbase);
        scan_groups<<<1, 1024, 0, stream>>>(gbase, G, counter);
        if (P == 1)
            accumulate_direct<<<((u32)n + 255) / 256, 256, 0, stream>>>(coords, kern, bitmap,
                                                                        wo16, gbase, feats, n);
        else
            accumulate_rec<<<gridB, 256, 0, stream>>>(records, pass_base, kern, bitmap, wo16,
                                                      gbase, feats, n, p, P, mask);
        emit_coords<<<(W + 255) / 256, 256, 0, stream>>>(bitmap, wo16, gbase, out_rows,
                                                         W, p, shift);
    }

    pad_fill<<<((u32)n + 255) / 256, 256, 0, stream>>>(out_rows, counter, n);
}